// Round 2
// baseline (367.610 us; speedup 1.0000x reference)
//
#include <hip/hip_runtime.h>
#include <stdint.h>

#define LEAKY 0.2f
#define NB 32768
#define HD 256

typedef __attribute__((ext_vector_type(8))) short short8;
typedef __attribute__((ext_vector_type(8))) unsigned short ushort8;
typedef __attribute__((ext_vector_type(4))) unsigned short ushort4v;
typedef __attribute__((ext_vector_type(4))) float f4;

static __device__ __forceinline__ float bf2f(unsigned short u) {
  union { unsigned int i; float f; } v; v.i = ((unsigned int)u) << 16; return v.f;
}
static __device__ __forceinline__ unsigned short f2bf(float f) {
  union { float f; unsigned int i; } v; v.f = f;
  return (unsigned short)((v.i + 0x7fffu + ((v.i >> 16) & 1u)) >> 16);  // RNE
}
static __device__ __forceinline__ ushort8 pack8(f4 a, f4 b) {
  ushort8 o;
  o[0] = f2bf(a[0]); o[1] = f2bf(a[1]); o[2] = f2bf(a[2]); o[3] = f2bf(a[3]);
  o[4] = f2bf(b[0]); o[5] = f2bf(b[1]); o[6] = f2bf(b[2]); o[7] = f2bf(b[3]);
  return o;
}
static __device__ __forceinline__ float sigm(float x) { return 1.f / (1.f + __expf(-x)); }
static __device__ __forceinline__ float tanha(float x) {
  float e = __expf(2.f * x);
  return 1.f - 2.f / (e + 1.f);   // finite for e -> inf
}

__device__ __forceinline__ void gload16(const void* g, void* s) {
  __builtin_amdgcn_global_load_lds(
      (const __attribute__((address_space(1))) unsigned int*)g,
      (__attribute__((address_space(3))) unsigned int*)s, 16, 0, 0);
}

// ---------------- prep kernels ----------------

// Wt[n*K + k] = bf16(W[k*N + n])   (transpose + convert; small matrices)
__global__ void wtrans(const float* __restrict__ W, unsigned short* __restrict__ Wt,
                       int K, int N) {
  int idx = blockIdx.x * 256 + threadIdx.x;
  if (idx >= K * N) return;
  int n = idx / K, k = idx - n * K;
  Wt[idx] = f2bf(W[(size_t)k * N + n]);
}

// Wkrt[n*512 + k]: k<256 -> Wk[k][n], else Wr[k-256][n]; N=1024, K=512
__global__ void wkrtrans(const float* __restrict__ Wk, const float* __restrict__ Wr,
                         unsigned short* __restrict__ Wt) {
  int idx = blockIdx.x * 256 + threadIdx.x;
  int n = idx >> 9, k = idx & 511;
  float v = (k < 256) ? Wk[(size_t)k * 1024 + n] : Wr[(size_t)(k - 256) * 1024 + n];
  Wt[idx] = f2bf(v);
}

// catb[:, :256] = bf16(x); csb[:, :256] = bf16(h); csb[:, 256:] = bf16(gather(h, vid))
__global__ void build_rows(const float* __restrict__ x, const float* __restrict__ h,
                           const int* __restrict__ vid,
                           unsigned short* __restrict__ catb,
                           unsigned short* __restrict__ csb) {
  int idx = blockIdx.x * 256 + threadIdx.x;   // NB*32 threads, 8 elems each
  int m = idx >> 5;
  int j = (idx & 31) << 3;
  f4 a0 = *(const f4*)(x + (size_t)m * 256 + j);
  f4 a1 = *(const f4*)(x + (size_t)m * 256 + j + 4);
  *(ushort8*)(catb + (size_t)m * 512 + j) = pack8(a0, a1);
  f4 h0 = *(const f4*)(h + (size_t)m * 256 + j);
  f4 h1 = *(const f4*)(h + (size_t)m * 256 + j + 4);
  *(ushort8*)(csb + (size_t)m * 512 + j) = pack8(h0, h1);
  int id = vid[m];
  f4 g0 = {0.f, 0.f, 0.f, 0.f}, g1 = {0.f, 0.f, 0.f, 0.f};
  if (id >= 0) {
    g0 = *(const f4*)(h + (size_t)id * 256 + j);
    g1 = *(const f4*)(h + (size_t)id * 256 + j + 4);
  }
  *(ushort8*)(csb + (size_t)m * 512 + 256 + j) = pack8(g0, g1);
}

// ---------------- GEMM: out = epilogue(A[M,K] @ Bt[N,K]^T + bias) ----------------
// MODE 0: leaky -> bf16 out.  MODE 1: leaky, fuse final_h = h + cs (vid>=0), write f32
// h_out slot + bf16 into catb[:,256:].  MODE 2: plain bias add -> bf16 (LSTM z).
template <int MODE>
__global__ __launch_bounds__(256, 2) void gemm_bf16(
    const unsigned short* __restrict__ A,   // [M, K] bf16 row-major
    const unsigned short* __restrict__ Bt,  // [N, K] bf16 row-major (B transposed)
    const float* __restrict__ bias,         // [N]
    int nTn, int K,
    unsigned short* __restrict__ outb, int ldo, int col_off,
    float* __restrict__ outf,               // MODE 1: f32 final_h (d_out h slot)
    const float* __restrict__ hst,          // MODE 1: h [B,256]
    const int* __restrict__ vid) {          // MODE 1
  __shared__ unsigned short sA[128 * 64];   // 16 KB, rows of 8 x 16B slots, XOR-swizzled
  __shared__ unsigned short sB[128 * 64];

  const int t = threadIdx.x;
  const int tm = blockIdx.x / nTn;
  const int tn = blockIdx.x - tm * nTn;
  const int wid = t >> 6, lane = t & 63;
  const int wr = wid >> 1, wc = wid & 1;          // 2x2 waves -> 64x64 each
  const int lrow = lane & 15, lkhi = lane >> 4;

  const unsigned short* Asrc = A + (size_t)tm * 128 * K;
  const unsigned short* Bsrc = Bt + (size_t)tn * 128 * K;
  const int rsub = t >> 3, slot = t & 7;

  f4 acc[4][4];
#pragma unroll
  for (int i = 0; i < 4; ++i)
#pragma unroll
    for (int j = 0; j < 4; ++j) acc[i][j] = {0.f, 0.f, 0.f, 0.f};

  for (int k0 = 0; k0 < K; k0 += 64) {
    // stage 128x64 bf16 tiles; linear LDS dest (lane*16), inverse-swizzled global src
#pragma unroll
    for (int iss = 0; iss < 4; ++iss) {
      int r = iss * 32 + rsub;
      int gs = slot ^ (r & 7);
      gload16(Asrc + (size_t)r * K + k0 + gs * 8, (char*)sA + r * 128 + slot * 16);
      gload16(Bsrc + (size_t)r * K + k0 + gs * 8, (char*)sB + r * 128 + slot * 16);
    }
    __syncthreads();   // drains vmcnt (global_load_lds) + barrier
#pragma unroll
    for (int kk = 0; kk < 2; ++kk) {
      short8 af[4], bf[4];
#pragma unroll
      for (int mi = 0; mi < 4; ++mi) {
        int row = wr * 64 + mi * 16 + lrow;
        int s = (kk * 4 + lkhi) ^ (row & 7);
        af[mi] = *(const short8*)&sA[row * 64 + s * 8];
      }
#pragma unroll
      for (int ni = 0; ni < 4; ++ni) {
        int rn = wc * 64 + ni * 16 + lrow;
        int s = (kk * 4 + lkhi) ^ (rn & 7);
        bf[ni] = *(const short8*)&sB[rn * 64 + s * 8];
      }
#pragma unroll
      for (int mi = 0; mi < 4; ++mi)
#pragma unroll
        for (int ni = 0; ni < 4; ++ni)
          acc[mi][ni] = __builtin_amdgcn_mfma_f32_16x16x32_bf16(af[mi], bf[ni],
                                                                acc[mi][ni], 0, 0, 0);
    }
    __syncthreads();
  }

  const int m_base = tm * 128 + wr * 64;
  const int n_base = tn * 128 + wc * 64;
  if (MODE == 1) {
#pragma unroll
    for (int mi = 0; mi < 4; ++mi) {
#pragma unroll
      for (int r = 0; r < 4; ++r) {
        int row = m_base + mi * 16 + lkhi * 4 + r;
        int id = vid[row];
#pragma unroll
        for (int ni = 0; ni < 4; ++ni) {
          int col = n_base + ni * 16 + lrow;
          float v = acc[mi][ni][r] + bias[col];
          v = v > 0.f ? v : LEAKY * v;
          float hv = hst[(size_t)row * HD + col];
          float fh = (id >= 0) ? hv + v : hv;
          outf[(size_t)row * HD + col] = fh;                       // f32 final_h
          outb[(size_t)row * ldo + col_off + col] = f2bf(fh);      // bf16 for LSTM GEMM
        }
      }
    }
  } else {
#pragma unroll
    for (int ni = 0; ni < 4; ++ni) {
      int col = n_base + ni * 16 + lrow;
      float bia = bias[col];
#pragma unroll
      for (int mi = 0; mi < 4; ++mi) {
#pragma unroll
        for (int r = 0; r < 4; ++r) {
          int row = m_base + mi * 16 + lkhi * 4 + r;
          float v = acc[mi][ni][r] + bia;
          if (MODE == 0) v = v > 0.f ? v : LEAKY * v;
          outb[(size_t)row * ldo + col_off + col] = f2bf(v);
        }
      }
    }
  }
}

// ---------------- LSTM elementwise ----------------
__global__ void lstm_ew(const unsigned short* __restrict__ zb,  // [B,1024] bf16: i,f,g,o
                        const float* __restrict__ cin,
                        const unsigned char* __restrict__ rs,
                        float* __restrict__ dout) {
  int idx = blockIdx.x * 256 + threadIdx.x;   // NB*64 threads, 4 cols each
  int m = idx >> 6;
  int n4 = (idx & 63) << 2;
  const unsigned short* zr = zb + (size_t)m * 1024 + n4;
  ushort4v zi = *(const ushort4v*)(zr);
  ushort4v zf = *(const ushort4v*)(zr + 256);
  ushort4v zg = *(const ushort4v*)(zr + 512);
  ushort4v zo = *(const ushort4v*)(zr + 768);
  size_t base = (size_t)m * HD + n4;
  float* outs = dout;
  float* houtp = dout + (size_t)NB * HD;
  float* coutp = dout + (size_t)2 * NB * HD;
  f4 c = *(const f4*)(cin + base);
  f4 fh = *(const f4*)(houtp + base);   // final_h written by L3 epilogue
  bool real = rs[0] != 0;
  f4 hn, ho, co;
#pragma unroll
  for (int e = 0; e < 4; ++e) {
    float i_ = sigm(bf2f(zi[e]));
    float f_ = sigm(bf2f(zf[e]));
    float g_ = tanha(bf2f(zg[e]));
    float o_ = sigm(bf2f(zo[e]));
    float cv = f_ * c[e] + i_ * g_;
    float hv = o_ * tanha(cv);
    hn[e] = hv;
    ho[e] = real ? hv : fh[e];
    co[e] = real ? cv : c[e];
  }
  *(f4*)(outs + base) = hn;
  *(f4*)(houtp + base) = ho;
  *(f4*)(coutp + base) = co;
}

// ---------------- launch ----------------
extern "C" void kernel_launch(void* const* d_in, const int* in_sizes, int n_in,
                              void* d_out, int out_size, void* d_ws, size_t ws_size,
                              hipStream_t stream) {
  const float* x = (const float*)d_in[0];
  const int* vid = (const int*)d_in[1];
  const unsigned char* rs = (const unsigned char*)d_in[2];
  const float* h = (const float*)d_in[3];
  const float* c = (const float*)d_in[4];
  const float* W1 = (const float*)d_in[5];
  const float* b1 = (const float*)d_in[6];
  const float* W2 = (const float*)d_in[7];
  const float* b2 = (const float*)d_in[8];
  const float* W3 = (const float*)d_in[9];
  const float* b3 = (const float*)d_in[10];
  const float* Wk = (const float*)d_in[11];
  const float* Wr = (const float*)d_in[12];
  const float* bl = (const float*)d_in[13];
  float* dout = (float*)d_out;

  char* ws = (char*)d_ws;
  unsigned short* W1t = (unsigned short*)(ws);                         // 512x512 bf16
  unsigned short* W2t = (unsigned short*)(ws + 524288);                // 512x512
  unsigned short* W3t = (unsigned short*)(ws + 1048576);               // 256x512
  unsigned short* Wkrt = (unsigned short*)(ws + 1310720);              // 1024x512
  unsigned short* bufA = (unsigned short*)(ws + 2359296);              // [B,512] bf16
  unsigned short* bufB = (unsigned short*)(ws + 2359296 + 33554432);   // [B,512] bf16
  unsigned short* catb = (unsigned short*)(ws + 2359296 + 67108864);   // [B,512] bf16
  unsigned short* zb = bufA;  // [B,1024] bf16, aliases bufA+bufB (free after L3)

  float* fhout = dout + (size_t)NB * HD;  // h_out slot doubles as f32 final_h

  wtrans<<<1024, 256, 0, stream>>>(W1, W1t, 512, 512);
  wtrans<<<1024, 256, 0, stream>>>(W2, W2t, 512, 512);
  wtrans<<<512, 256, 0, stream>>>(W3, W3t, 512, 256);
  wkrtrans<<<2048, 256, 0, stream>>>(Wk, Wr, Wkrt);
  build_rows<<<NB * 32 / 256, 256, 0, stream>>>(x, h, vid, catb, bufA);

  // L1: bufB = leaky(cs0 @ W1 + b1)
  gemm_bf16<0><<<(NB / 128) * 4, 256, 0, stream>>>(bufA, W1t, b1, 4, 512,
                                                   bufB, 512, 0, nullptr, nullptr, nullptr);
  // L2: bufA = leaky(a1 @ W2 + b2)
  gemm_bf16<0><<<(NB / 128) * 4, 256, 0, stream>>>(bufB, W2t, b2, 4, 512,
                                                   bufA, 512, 0, nullptr, nullptr, nullptr);
  // L3: cs = leaky(a2 @ W3 + b3); final_h = h + cs (vid>=0); -> fhout f32 + catb[:,256:]
  gemm_bf16<1><<<(NB / 128) * 2, 256, 0, stream>>>(bufA, W3t, b3, 2, 512,
                                                   catb, 512, 256, fhout, h, vid);
  // LSTM: z = [x, fh] @ [Wk; Wr] + bl -> zb bf16
  gemm_bf16<2><<<(NB / 128) * 8, 256, 0, stream>>>(catb, Wkrt, bl, 8, 512,
                                                   zb, 1024, 0, nullptr, nullptr, nullptr);
  lstm_ew<<<NB * 64 / 256, 256, 0, stream>>>(zb, c, rs, dout);
}

// Round 3
// 351.292 us; speedup vs baseline: 1.0464x; 1.0464x over previous
//
#include <hip/hip_runtime.h>
#include <stdint.h>

#define LEAKY 0.2f
#define NB 32768
#define HD 256

typedef __attribute__((ext_vector_type(8))) short short8;
typedef __attribute__((ext_vector_type(8))) unsigned short ushort8;
typedef __attribute__((ext_vector_type(4))) float f4;

static __device__ __forceinline__ float bf2f(unsigned short u) {
  union { unsigned int i; float f; } v; v.i = ((unsigned int)u) << 16; return v.f;
}
static __device__ __forceinline__ unsigned short f2bf(float f) {
  union { float f; unsigned int i; } v; v.f = f;
  return (unsigned short)((v.i + 0x7fffu + ((v.i >> 16) & 1u)) >> 16);  // RNE
}
static __device__ __forceinline__ ushort8 pack8(f4 a, f4 b) {
  ushort8 o;
  o[0] = f2bf(a[0]); o[1] = f2bf(a[1]); o[2] = f2bf(a[2]); o[3] = f2bf(a[3]);
  o[4] = f2bf(b[0]); o[5] = f2bf(b[1]); o[6] = f2bf(b[2]); o[7] = f2bf(b[3]);
  return o;
}
static __device__ __forceinline__ float sigm(float x) { return 1.f / (1.f + __expf(-x)); }
static __device__ __forceinline__ float tanha(float x) {
  float e = __expf(2.f * x);
  return 1.f - 2.f / (e + 1.f);   // finite for e -> inf
}

__device__ __forceinline__ void gload16(const void* g, void* s) {
  __builtin_amdgcn_global_load_lds(
      (const __attribute__((address_space(1))) unsigned int*)g,
      (__attribute__((address_space(3))) unsigned int*)s, 16, 0, 0);
}

// ---------------- merged weight prep (1 launch) ----------------
// W1t/W2t/W3t: Wt[n*512 + k] = bf16(W[k*N + n])  (B pre-transposed to [N,K])
// Wkrt: LSTM B with gate-interleaved row order so GEMM wave fragment ni == gate:
//   Bt_row = (hcol>>5)*128 + ((hcol>>4)&1)*64 + gate*16 + (hcol&15)
__global__ void wprep(const float* __restrict__ W1, const float* __restrict__ W2,
                      const float* __restrict__ W3, const float* __restrict__ Wk,
                      const float* __restrict__ Wr,
                      unsigned short* __restrict__ W1t, unsigned short* __restrict__ W2t,
                      unsigned short* __restrict__ W3t, unsigned short* __restrict__ Wkrt) {
  int idx = blockIdx.x * 256 + threadIdx.x;
  if (idx < 262144) {                       // W1 [512,512]
    int n = idx >> 9, k = idx & 511;
    W1t[idx] = f2bf(W1[k * 512 + n]);
  } else if (idx < 524288) {                // W2 [512,512]
    int j = idx - 262144;
    int n = j >> 9, k = j & 511;
    W2t[j] = f2bf(W2[k * 512 + n]);
  } else if (idx < 655360) {                // W3 [512,256] -> W3t [256,512]
    int j = idx - 524288;
    int n = j >> 9, k = j & 511;
    W3t[j] = f2bf(W3[k * 256 + n]);
  } else {                                  // Wkrt [1024,512], gate-interleaved rows
    int j = idx - 655360;
    int rbt = j >> 9, k = j & 511;
    int gate = (rbt >> 4) & 3;
    int hcol = (rbt >> 7) * 32 + ((rbt >> 6) & 1) * 16 + (rbt & 15);
    int ocol = gate * 256 + hcol;
    float v = (k < 256) ? Wk[k * 1024 + ocol] : Wr[(k - 256) * 1024 + ocol];
    Wkrt[j] = f2bf(v);
  }
}

// catb[:, :256] = bf16(x); csb[:, :256] = bf16(h); csb[:, 256:] = bf16(gather(h, vid))
__global__ void build_rows(const float* __restrict__ x, const float* __restrict__ h,
                           const int* __restrict__ vid,
                           unsigned short* __restrict__ catb,
                           unsigned short* __restrict__ csb) {
  int idx = blockIdx.x * 256 + threadIdx.x;   // NB*32 threads, 8 elems each
  int m = idx >> 5;
  int j = (idx & 31) << 3;
  f4 a0 = *(const f4*)(x + (size_t)m * 256 + j);
  f4 a1 = *(const f4*)(x + (size_t)m * 256 + j + 4);
  *(ushort8*)(catb + (size_t)m * 512 + j) = pack8(a0, a1);
  f4 h0 = *(const f4*)(h + (size_t)m * 256 + j);
  f4 h1 = *(const f4*)(h + (size_t)m * 256 + j + 4);
  *(ushort8*)(csb + (size_t)m * 512 + j) = pack8(h0, h1);
  int id = vid[m];
  f4 g0 = {0.f, 0.f, 0.f, 0.f}, g1 = {0.f, 0.f, 0.f, 0.f};
  if (id >= 0) {
    g0 = *(const f4*)(h + (size_t)id * 256 + j);
    g1 = *(const f4*)(h + (size_t)id * 256 + j + 4);
  }
  *(ushort8*)(csb + (size_t)m * 512 + 256 + j) = pack8(g0, g1);
}

// ---------------- GEMM: epilogue(A[M,K] @ Bt[N,K]^T + bias) ----------------
// MODE 0: leaky -> bf16. MODE 1: leaky + final_h = h + cs (vid>=0) -> f32 h slot +
// bf16 catb[:,256:]. MODE 3: fused LSTM cell (gate-interleaved Bt) -> 3 f32 outputs.
template <int MODE>
__global__ __launch_bounds__(256, 2) void gemm_bf16(
    const unsigned short* __restrict__ A,   // [M, K] bf16 row-major
    const unsigned short* __restrict__ Bt,  // [N, K] bf16 row-major
    const float* __restrict__ bias,         // [N] (MODE3: original gate*256+hcol order)
    int nTn, int K,
    unsigned short* __restrict__ outb, int ldo, int col_off,
    float* __restrict__ outf,               // MODE1: f32 final_h; MODE3: d_out base
    const float* __restrict__ hst,          // MODE1: h
    const int* __restrict__ vid,            // MODE1
    const float* __restrict__ cin,          // MODE3: c
    const unsigned char* __restrict__ rsp) {// MODE3: real_step
  __shared__ unsigned short sA[128 * 64];   // 16 KB, 8 x 16B slots/row, XOR-swizzled
  __shared__ unsigned short sB[128 * 64];

  const int t = threadIdx.x;
  const int tm = blockIdx.x / nTn;
  const int tn = blockIdx.x - tm * nTn;
  const int wid = t >> 6, lane = t & 63;
  const int wr = wid >> 1, wc = wid & 1;          // 2x2 waves -> 64x64 each
  const int lrow = lane & 15, lkhi = lane >> 4;

  const unsigned short* Asrc = A + (size_t)tm * 128 * K;
  const unsigned short* Bsrc = Bt + (size_t)tn * 128 * K;
  const int rsub = t >> 3, slot = t & 7;

  f4 acc[4][4];
#pragma unroll
  for (int i = 0; i < 4; ++i)
#pragma unroll
    for (int j = 0; j < 4; ++j) acc[i][j] = {0.f, 0.f, 0.f, 0.f};

  for (int k0 = 0; k0 < K; k0 += 64) {
    // stage 128x64 bf16 tiles; linear LDS dest, inverse-swizzled global src (G21)
#pragma unroll
    for (int iss = 0; iss < 4; ++iss) {
      int r = iss * 32 + rsub;
      int gs = slot ^ (r & 7);
      gload16(Asrc + (size_t)r * K + k0 + gs * 8, (char*)sA + r * 128 + slot * 16);
      gload16(Bsrc + (size_t)r * K + k0 + gs * 8, (char*)sB + r * 128 + slot * 16);
    }
    __syncthreads();
#pragma unroll
    for (int kk = 0; kk < 2; ++kk) {
      short8 af[4], bfr[4];
#pragma unroll
      for (int mi = 0; mi < 4; ++mi) {
        int row = wr * 64 + mi * 16 + lrow;
        int s = (kk * 4 + lkhi) ^ (row & 7);
        af[mi] = *(const short8*)&sA[row * 64 + s * 8];
      }
#pragma unroll
      for (int ni = 0; ni < 4; ++ni) {
        int rn = wc * 64 + ni * 16 + lrow;
        int s = (kk * 4 + lkhi) ^ (rn & 7);
        bfr[ni] = *(const short8*)&sB[rn * 64 + s * 8];
      }
#pragma unroll
      for (int mi = 0; mi < 4; ++mi)
#pragma unroll
        for (int ni = 0; ni < 4; ++ni)
          acc[mi][ni] = __builtin_amdgcn_mfma_f32_16x16x32_bf16(af[mi], bfr[ni],
                                                                acc[mi][ni], 0, 0, 0);
    }
    __syncthreads();
  }

  const int m_base = tm * 128 + wr * 64;
  const int n_base = tn * 128 + wc * 64;
  if (MODE == 1) {
#pragma unroll
    for (int mi = 0; mi < 4; ++mi) {
#pragma unroll
      for (int r = 0; r < 4; ++r) {
        int row = m_base + mi * 16 + lkhi * 4 + r;
        int id = vid[row];
#pragma unroll
        for (int ni = 0; ni < 4; ++ni) {
          int col = n_base + ni * 16 + lrow;
          float v = acc[mi][ni][r] + bias[col];
          v = v > 0.f ? v : LEAKY * v;
          float hv = hst[(size_t)row * HD + col];
          float fh = (id >= 0) ? hv + v : hv;
          outf[(size_t)row * HD + col] = fh;                       // f32 final_h
          outb[(size_t)row * ldo + col_off + col] = f2bf(fh);      // bf16 for LSTM GEMM
        }
      }
    }
  } else if (MODE == 3) {
    const bool real = rsp[0] != 0;
    const int hcol = tn * 32 + wc * 16 + lrow;
    const float bi = bias[hcol];
    const float bff = bias[256 + hcol];
    const float bg = bias[512 + hcol];
    const float bo = bias[768 + hcol];
    float* outs = outf;
    float* houtp = outf + (size_t)NB * HD;
    float* coutp = outf + (size_t)2 * NB * HD;
#pragma unroll
    for (int mi = 0; mi < 4; ++mi) {
#pragma unroll
      for (int r = 0; r < 4; ++r) {
        int row = m_base + mi * 16 + lkhi * 4 + r;
        size_t base = (size_t)row * HD + hcol;
        float cold = cin[base];
        float i_ = sigm(acc[mi][0][r] + bi);
        float f_ = sigm(acc[mi][1][r] + bff);
        float g_ = tanha(acc[mi][2][r] + bg);
        float o_ = sigm(acc[mi][3][r] + bo);
        float cv = f_ * cold + i_ * g_;
        float hv = o_ * tanha(cv);
        outs[base] = hv;
        // h_out: final_h (already there from MODE1) when !real; c_out: c when !real
        if (real) {
          houtp[base] = hv;
          coutp[base] = cv;
        } else {
          coutp[base] = cold;
        }
      }
    }
  } else {  // MODE 0
#pragma unroll
    for (int ni = 0; ni < 4; ++ni) {
      int col = n_base + ni * 16 + lrow;
      float bia = bias[col];
#pragma unroll
      for (int mi = 0; mi < 4; ++mi) {
#pragma unroll
        for (int r = 0; r < 4; ++r) {
          int row = m_base + mi * 16 + lkhi * 4 + r;
          float v = acc[mi][ni][r] + bia;
          v = v > 0.f ? v : LEAKY * v;
          outb[(size_t)row * ldo + col_off + col] = f2bf(v);
        }
      }
    }
  }
}

// ---------------- launch ----------------
extern "C" void kernel_launch(void* const* d_in, const int* in_sizes, int n_in,
                              void* d_out, int out_size, void* d_ws, size_t ws_size,
                              hipStream_t stream) {
  const float* x = (const float*)d_in[0];
  const int* vid = (const int*)d_in[1];
  const unsigned char* rs = (const unsigned char*)d_in[2];
  const float* h = (const float*)d_in[3];
  const float* c = (const float*)d_in[4];
  const float* W1 = (const float*)d_in[5];
  const float* b1 = (const float*)d_in[6];
  const float* W2 = (const float*)d_in[7];
  const float* b2 = (const float*)d_in[8];
  const float* W3 = (const float*)d_in[9];
  const float* b3 = (const float*)d_in[10];
  const float* Wk = (const float*)d_in[11];
  const float* Wr = (const float*)d_in[12];
  const float* bl = (const float*)d_in[13];
  float* dout = (float*)d_out;

  char* ws = (char*)d_ws;
  unsigned short* W1t = (unsigned short*)(ws);                         // 512x512 bf16
  unsigned short* W2t = (unsigned short*)(ws + 524288);                // 512x512
  unsigned short* W3t = (unsigned short*)(ws + 1048576);               // 256x512
  unsigned short* Wkrt = (unsigned short*)(ws + 1310720);              // 1024x512
  unsigned short* bufA = (unsigned short*)(ws + 2359296);              // [B,512] bf16
  unsigned short* bufB = (unsigned short*)(ws + 2359296 + 33554432);   // [B,512] bf16
  unsigned short* catb = (unsigned short*)(ws + 2359296 + 67108864);   // [B,512] bf16

  float* fhout = dout + (size_t)NB * HD;  // h_out slot doubles as f32 final_h

  wprep<<<4608, 256, 0, stream>>>(W1, W2, W3, Wk, Wr, W1t, W2t, W3t, Wkrt);
  build_rows<<<NB * 32 / 256, 256, 0, stream>>>(x, h, vid, catb, bufA);

  // L1: bufB = leaky(cs0 @ W1 + b1)
  gemm_bf16<0><<<(NB / 128) * 4, 256, 0, stream>>>(
      bufA, W1t, b1, 4, 512, bufB, 512, 0, nullptr, nullptr, nullptr, nullptr, nullptr);
  // L2: bufA = leaky(a1 @ W2 + b2)
  gemm_bf16<0><<<(NB / 128) * 4, 256, 0, stream>>>(
      bufB, W2t, b2, 4, 512, bufA, 512, 0, nullptr, nullptr, nullptr, nullptr, nullptr);
  // L3: cs = leaky(a2 @ W3 + b3); final_h = h + cs (vid>=0) -> fhout f32 + catb[:,256:]
  gemm_bf16<1><<<(NB / 128) * 2, 256, 0, stream>>>(
      bufA, W3t, b3, 2, 512, catb, 512, 256, fhout, h, vid, nullptr, nullptr);
  // LSTM: z = [x, fh] @ Wkrt^T + bl, gates fused in-register -> outputs/h_out/c_out
  gemm_bf16<3><<<(NB / 128) * 8, 256, 0, stream>>>(
      catb, Wkrt, bl, 8, 512, nullptr, 0, 0, dout, nullptr, nullptr, c, rs);
}

// Round 4
// 345.238 us; speedup vs baseline: 1.0648x; 1.0175x over previous
//
#include <hip/hip_runtime.h>
#include <stdint.h>

#define LEAKY 0.2f
#define NB 32768
#define HD 256

typedef __attribute__((ext_vector_type(8))) short short8;
typedef __attribute__((ext_vector_type(8))) unsigned short ushort8;
typedef __attribute__((ext_vector_type(4))) float f4;

static __device__ __forceinline__ float bf2f(unsigned short u) {
  union { unsigned int i; float f; } v; v.i = ((unsigned int)u) << 16; return v.f;
}
static __device__ __forceinline__ unsigned short f2bf(float f) {
  union { float f; unsigned int i; } v; v.f = f;
  return (unsigned short)((v.i + 0x7fffu + ((v.i >> 16) & 1u)) >> 16);  // RNE
}
static __device__ __forceinline__ ushort8 pack8(f4 a, f4 b) {
  ushort8 o;
  o[0] = f2bf(a[0]); o[1] = f2bf(a[1]); o[2] = f2bf(a[2]); o[3] = f2bf(a[3]);
  o[4] = f2bf(b[0]); o[5] = f2bf(b[1]); o[6] = f2bf(b[2]); o[7] = f2bf(b[3]);
  return o;
}
static __device__ __forceinline__ float sigm(float x) { return 1.f / (1.f + __expf(-x)); }
static __device__ __forceinline__ float tanha(float x) {
  float e = __expf(2.f * x);
  return 1.f - 2.f / (e + 1.f);   // finite for e -> inf
}

__device__ __forceinline__ void gload16(const void* g, void* s) {
  __builtin_amdgcn_global_load_lds(
      (const __attribute__((address_space(1))) unsigned int*)g,
      (__attribute__((address_space(3))) unsigned int*)s, 16, 0, 0);
}

// ---------------- weight prep: LDS-tiled transpose, 1 launch ----------------
// Logical source S[k][n] (f32), output Wt[perm(n)][k] (bf16).
// Block tiles 64x64. Tile map: [0,64) W1 8x8; [64,128) W2 8x8; [128,160) W3 8x4;
// [160,288) Wkr 8x16 (n = ocol in [0,1024), k<256 -> Wk else Wr; perm = gate interleave).
__global__ void wprep(const float* __restrict__ W1, const float* __restrict__ W2,
                      const float* __restrict__ W3, const float* __restrict__ Wk,
                      const float* __restrict__ Wr,
                      unsigned short* __restrict__ W1t, unsigned short* __restrict__ W2t,
                      unsigned short* __restrict__ W3t, unsigned short* __restrict__ Wkrt) {
  __shared__ float tile[64][65];
  const int id = blockIdx.x, t = threadIdx.x;
  const int tr = t >> 6, tc = t & 63;   // 4 rows per pass, 16 passes

  const float* src;
  unsigned short* dst;
  int kbase, nbase, srcld, perm = 0;
  if (id < 64) {
    src = W1; dst = W1t; srcld = 512;
    kbase = (id >> 3) * 64; nbase = (id & 7) * 64;
  } else if (id < 128) {
    src = W2; dst = W2t; srcld = 512;
    kbase = ((id - 64) >> 3) * 64; nbase = ((id - 64) & 7) * 64;
  } else if (id < 160) {
    src = W3; dst = W3t; srcld = 256;
    kbase = ((id - 128) >> 2) * 64; nbase = ((id - 128) & 3) * 64;
  } else {
    src = nullptr; dst = Wkrt; srcld = 1024; perm = 1;
    kbase = ((id - 160) >> 4) * 64; nbase = ((id - 160) & 15) * 64;
  }

#pragma unroll
  for (int p = 0; p < 16; ++p) {
    int r = p * 4 + tr;             // k offset within tile
    int k = kbase + r, n = nbase + tc;
    float v;
    if (perm) {
      v = (k < 256) ? Wk[k * 1024 + n] : Wr[(k - 256) * 1024 + n];
    } else {
      v = src[k * srcld + n];
    }
    tile[r][tc] = v;
  }
  __syncthreads();
#pragma unroll
  for (int p = 0; p < 16; ++p) {
    int c = p * 4 + tr;             // n offset within tile
    int n = nbase + c;
    int orow;
    if (perm) {
      int gate = n >> 8, hcol = n & 255;
      orow = (hcol >> 5) * 128 + ((hcol >> 4) & 1) * 64 + gate * 16 + (hcol & 15);
    } else {
      orow = n;
    }
    dst[orow * 512 + kbase + tc] = f2bf(tile[tc][c]);
  }
}

// catb[:, :256] = bf16(x); csb[:, :256] = bf16(h); csb[:, 256:] = bf16(gather(h, vid))
__global__ void build_rows(const float* __restrict__ x, const float* __restrict__ h,
                           const int* __restrict__ vid,
                           unsigned short* __restrict__ catb,
                           unsigned short* __restrict__ csb) {
  int idx = blockIdx.x * 256 + threadIdx.x;   // NB*32 threads, 8 elems each
  int m = idx >> 5;
  int j = (idx & 31) << 3;
  f4 a0 = *(const f4*)(x + (size_t)m * 256 + j);
  f4 a1 = *(const f4*)(x + (size_t)m * 256 + j + 4);
  *(ushort8*)(catb + (size_t)m * 512 + j) = pack8(a0, a1);
  f4 h0 = *(const f4*)(h + (size_t)m * 256 + j);
  f4 h1 = *(const f4*)(h + (size_t)m * 256 + j + 4);
  *(ushort8*)(csb + (size_t)m * 512 + j) = pack8(h0, h1);
  int id = vid[m];
  f4 g0 = {0.f, 0.f, 0.f, 0.f}, g1 = {0.f, 0.f, 0.f, 0.f};
  if (id >= 0) {
    g0 = *(const f4*)(h + (size_t)id * 256 + j);
    g1 = *(const f4*)(h + (size_t)id * 256 + j + 4);
  }
  *(ushort8*)(csb + (size_t)m * 512 + 256 + j) = pack8(g0, g1);
}

// ---------------- GEMM: epilogue(A[M,K] @ Bt[N,K]^T + bias) ----------------
// XCD-colocating swizzle: all NTN column-tiles of one row-tile land on one XCD so the
// shared A-tile is fetched into that XCD's L2 once (T1; grid%8==0 for all calls).
// MODE 0: leaky -> bf16. MODE 1: leaky + final_h = h + cs (vid>=0) -> f32 h slot +
// bf16 catb[:,256:]. MODE 3: fused LSTM cell (gate-interleaved Bt) -> 3 f32 outputs.
template <int MODE, int NTN>
__global__ __launch_bounds__(256, 4) void gemm_bf16(
    const unsigned short* __restrict__ A,   // [M, K] bf16 row-major
    const unsigned short* __restrict__ Bt,  // [N, K] bf16 row-major
    const float* __restrict__ bias,         // [N] (MODE3: original gate*256+hcol order)
    int K,
    unsigned short* __restrict__ outb, int ldo, int col_off,
    float* __restrict__ outf,               // MODE1: f32 final_h; MODE3: d_out base
    const float* __restrict__ hst,          // MODE1: h
    const int* __restrict__ vid,            // MODE1
    const float* __restrict__ cin,          // MODE3: c
    const unsigned char* __restrict__ rsp) {// MODE3: real_step
  __shared__ unsigned short sA[128 * 64];   // 16 KB, 8 x 16B slots/row, XOR-swizzled
  __shared__ unsigned short sB[128 * 64];

  const int t = threadIdx.x;
  const int p = blockIdx.x;
  const int xcd = p & 7, local = p >> 3;
  const int tm = xcd + ((local / NTN) << 3);
  const int tn = local % NTN;
  const int wid = t >> 6, lane = t & 63;
  const int wr = wid >> 1, wc = wid & 1;          // 2x2 waves -> 64x64 each
  const int lrow = lane & 15, lkhi = lane >> 4;

  const unsigned short* Asrc = A + (size_t)tm * 128 * K;
  const unsigned short* Bsrc = Bt + (size_t)tn * 128 * K;
  const int rsub = t >> 3, slot = t & 7;

  f4 acc[4][4];
#pragma unroll
  for (int i = 0; i < 4; ++i)
#pragma unroll
    for (int j = 0; j < 4; ++j) acc[i][j] = {0.f, 0.f, 0.f, 0.f};

  for (int k0 = 0; k0 < K; k0 += 64) {
    // stage 128x64 bf16 tiles; linear LDS dest, inverse-swizzled global src (G21)
#pragma unroll
    for (int iss = 0; iss < 4; ++iss) {
      int r = iss * 32 + rsub;
      int gs = slot ^ (r & 7);
      gload16(Asrc + (size_t)r * K + k0 + gs * 8, (char*)sA + r * 128 + slot * 16);
      gload16(Bsrc + (size_t)r * K + k0 + gs * 8, (char*)sB + r * 128 + slot * 16);
    }
    __syncthreads();
#pragma unroll
    for (int kk = 0; kk < 2; ++kk) {
      short8 af[4], bfr[4];
#pragma unroll
      for (int mi = 0; mi < 4; ++mi) {
        int row = wr * 64 + mi * 16 + lrow;
        int s = (kk * 4 + lkhi) ^ (row & 7);
        af[mi] = *(const short8*)&sA[row * 64 + s * 8];
      }
#pragma unroll
      for (int ni = 0; ni < 4; ++ni) {
        int rn = wc * 64 + ni * 16 + lrow;
        int s = (kk * 4 + lkhi) ^ (rn & 7);
        bfr[ni] = *(const short8*)&sB[rn * 64 + s * 8];
      }
#pragma unroll
      for (int mi = 0; mi < 4; ++mi)
#pragma unroll
        for (int ni = 0; ni < 4; ++ni)
          acc[mi][ni] = __builtin_amdgcn_mfma_f32_16x16x32_bf16(af[mi], bfr[ni],
                                                                acc[mi][ni], 0, 0, 0);
    }
    __syncthreads();
  }

  const int m_base = tm * 128 + wr * 64;
  const int n_base = tn * 128 + wc * 64;
  if (MODE == 1) {
#pragma unroll
    for (int mi = 0; mi < 4; ++mi) {
#pragma unroll
      for (int r = 0; r < 4; ++r) {
        int row = m_base + mi * 16 + lkhi * 4 + r;
        int id = vid[row];
#pragma unroll
        for (int ni = 0; ni < 4; ++ni) {
          int col = n_base + ni * 16 + lrow;
          float v = acc[mi][ni][r] + bias[col];
          v = v > 0.f ? v : LEAKY * v;
          float hv = hst[(size_t)row * HD + col];
          float fh = (id >= 0) ? hv + v : hv;
          outf[(size_t)row * HD + col] = fh;                       // f32 final_h
          outb[(size_t)row * ldo + col_off + col] = f2bf(fh);      // bf16 for LSTM GEMM
        }
      }
    }
  } else if (MODE == 3) {
    const bool real = rsp[0] != 0;
    const int hcol = tn * 32 + wc * 16 + lrow;
    const float bi = bias[hcol];
    const float bff = bias[256 + hcol];
    const float bg = bias[512 + hcol];
    const float bo = bias[768 + hcol];
    float* outs = outf;
    float* houtp = outf + (size_t)NB * HD;
    float* coutp = outf + (size_t)2 * NB * HD;
#pragma unroll
    for (int mi = 0; mi < 4; ++mi) {
#pragma unroll
      for (int r = 0; r < 4; ++r) {
        int row = m_base + mi * 16 + lkhi * 4 + r;
        size_t base = (size_t)row * HD + hcol;
        float cold = cin[base];
        float i_ = sigm(acc[mi][0][r] + bi);
        float f_ = sigm(acc[mi][1][r] + bff);
        float g_ = tanha(acc[mi][2][r] + bg);
        float o_ = sigm(acc[mi][3][r] + bo);
        float cv = f_ * cold + i_ * g_;
        float hv = o_ * tanha(cv);
        outs[base] = hv;
        // h_out: final_h (already there from MODE1) when !real; c_out: c when !real
        if (real) {
          houtp[base] = hv;
          coutp[base] = cv;
        } else {
          coutp[base] = cold;
        }
      }
    }
  } else {  // MODE 0
#pragma unroll
    for (int ni = 0; ni < 4; ++ni) {
      int col = n_base + ni * 16 + lrow;
      float bia = bias[col];
#pragma unroll
      for (int mi = 0; mi < 4; ++mi) {
#pragma unroll
        for (int r = 0; r < 4; ++r) {
          int row = m_base + mi * 16 + lkhi * 4 + r;
          float v = acc[mi][ni][r] + bia;
          v = v > 0.f ? v : LEAKY * v;
          outb[(size_t)row * ldo + col_off + col] = f2bf(v);
        }
      }
    }
  }
}

// ---------------- launch ----------------
extern "C" void kernel_launch(void* const* d_in, const int* in_sizes, int n_in,
                              void* d_out, int out_size, void* d_ws, size_t ws_size,
                              hipStream_t stream) {
  const float* x = (const float*)d_in[0];
  const int* vid = (const int*)d_in[1];
  const unsigned char* rs = (const unsigned char*)d_in[2];
  const float* h = (const float*)d_in[3];
  const float* c = (const float*)d_in[4];
  const float* W1 = (const float*)d_in[5];
  const float* b1 = (const float*)d_in[6];
  const float* W2 = (const float*)d_in[7];
  const float* b2 = (const float*)d_in[8];
  const float* W3 = (const float*)d_in[9];
  const float* b3 = (const float*)d_in[10];
  const float* Wk = (const float*)d_in[11];
  const float* Wr = (const float*)d_in[12];
  const float* bl = (const float*)d_in[13];
  float* dout = (float*)d_out;

  char* ws = (char*)d_ws;
  unsigned short* W1t = (unsigned short*)(ws);                         // 512x512 bf16
  unsigned short* W2t = (unsigned short*)(ws + 524288);                // 512x512
  unsigned short* W3t = (unsigned short*)(ws + 1048576);               // 256x512
  unsigned short* Wkrt = (unsigned short*)(ws + 1310720);              // 1024x512
  unsigned short* bufA = (unsigned short*)(ws + 2359296);              // [B,512] bf16
  unsigned short* bufB = (unsigned short*)(ws + 2359296 + 33554432);   // [B,512] bf16
  unsigned short* catb = (unsigned short*)(ws + 2359296 + 67108864);   // [B,512] bf16

  float* fhout = dout + (size_t)NB * HD;  // h_out slot doubles as f32 final_h

  wprep<<<288, 256, 0, stream>>>(W1, W2, W3, Wk, Wr, W1t, W2t, W3t, Wkrt);
  build_rows<<<NB * 32 / 256, 256, 0, stream>>>(x, h, vid, catb, bufA);

  // L1: bufB = leaky(cs0 @ W1 + b1)
  gemm_bf16<0, 4><<<(NB / 128) * 4, 256, 0, stream>>>(
      bufA, W1t, b1, 512, bufB, 512, 0, nullptr, nullptr, nullptr, nullptr, nullptr);
  // L2: bufA = leaky(a1 @ W2 + b2)
  gemm_bf16<0, 4><<<(NB / 128) * 4, 256, 0, stream>>>(
      bufB, W2t, b2, 512, bufA, 512, 0, nullptr, nullptr, nullptr, nullptr, nullptr);
  // L3: cs = leaky(a2 @ W3 + b3); final_h = h + cs (vid>=0) -> fhout f32 + catb[:,256:]
  gemm_bf16<1, 2><<<(NB / 128) * 2, 256, 0, stream>>>(
      bufA, W3t, b3, 512, catb, 512, 256, fhout, h, vid, nullptr, nullptr);
  // LSTM: z = [x, fh] @ Wkrt^T + bl, gates fused in-register -> outputs/h_out/c_out
  gemm_bf16<3, 8><<<(NB / 128) * 8, 256, 0, stream>>>(
      catb, Wkrt, bl, 512, nullptr, 0, 0, dout, nullptr, nullptr, c, rs);
}